// Round 1
// baseline (529.170 us; speedup 1.0000x reference)
//
#include <hip/hip_runtime.h>
#include <math.h>

#define EPS 1e-5f

// ---------------------------------------------------------------------------
// Pipeline (all BN folded into adjacent matmuls; GCN aggregation done on the
// 128-dim Y features BEFORE W_gcn thanks to linearity):
//  1. col stats of X [N,512]
//  2. fold BN1 into W_mlp -> W1p, b1p
//  3. Y = relu(X @ W1p + b1p)  + col stats of Y (for BN2)
//  4. in-degree count, exclusive scan -> CSR, dinv = rsqrt(deg+1)
//  5. fold BN2 into W_gcn -> W2p, hconst
//  6. gather: A[d] = dinv[d]*(sum_in dinv[s]*Y[s] + dinv[d]*Y[d]); scoef[d]
//  7. final: U = A@W2p + hconst*scoef + b_gcn; relu; logits=U@Wcls+bcls; logsoftmax
// ---------------------------------------------------------------------------

__global__ void k_zero(float* __restrict__ p, int n) {
  int i = blockIdx.x * 256 + threadIdx.x;
  if (i < n) p[i] = 0.f;
}

// ---------- BN1 column stats over X [N,512] ----------
__global__ __launch_bounds__(512)
void k_bn1_stats(const float* __restrict__ X, int N,
                 float* __restrict__ s, float* __restrict__ q) {
  int c = threadIdx.x;
  float sum = 0.f, sq = 0.f;
  for (int r = blockIdx.x; r < N; r += gridDim.x) {
    float v = X[(size_t)r * 512 + c];
    sum += v;
    sq += v * v;
  }
  atomicAdd(&s[c], sum);
  atomicAdd(&q[c], sq);
}

// ---------- fold BN scale into weights: Wp[k][j] = a[k]*W[k][j] (128 cols) ----------
__global__ void k_foldw(const float* __restrict__ s, const float* __restrict__ q,
                        const float* __restrict__ gamma, const float* __restrict__ beta,
                        const float* __restrict__ W, float* __restrict__ Wp, float invN) {
  int idx = blockIdx.x * blockDim.x + threadIdx.x;
  int k = idx >> 7;
  float mu = s[k] * invN;
  float var = fmaxf(q[k] * invN - mu * mu, 0.f);
  float a = gamma[k] * rsqrtf(var + EPS);
  Wp[idx] = a * W[idx];
}

// ---------- fold BN shift: bp[j] = (b?b[j]:0) + sum_k c[k]*W[k][j] ----------
__global__ void k_foldb(const float* __restrict__ s, const float* __restrict__ q,
                        const float* __restrict__ gamma, const float* __restrict__ beta,
                        const float* __restrict__ W, const float* __restrict__ b,
                        float* __restrict__ bp, float invN, int K) {
  int j = threadIdx.x;  // 0..127
  float acc = b ? b[j] : 0.f;
  for (int k = 0; k < K; ++k) {
    float mu = s[k] * invN;
    float var = fmaxf(q[k] * invN - mu * mu, 0.f);
    float a = gamma[k] * rsqrtf(var + EPS);
    float c = beta[k] - mu * a;
    acc += c * W[k * 128 + j];
  }
  bp[j] = acc;
}

// ---------- GEMM1: Y = relu(X[N,512] @ Wp[512,128] + bp); col sums/sumsq of Y ----------
// BM=64 rows, BN=128 cols, BK=32. 256 thr: micro-tile 8 rows x 4 cols.
__global__ __launch_bounds__(256)
void k_gemm1(const float* __restrict__ X, const float* __restrict__ Wp,
             const float* __restrict__ bp, float* __restrict__ Y,
             float* __restrict__ s2, float* __restrict__ q2, int N) {
  __shared__ __align__(16) float XsT[32 * 68];   // [kk][r], pad 68 vs 64
  __shared__ __align__(16) float Ws[32 * 128];   // [kk][j]
  __shared__ float csum[128], cq[128];
  int tid = threadIdx.x;
  if (tid < 128) { csum[tid] = 0.f; cq[tid] = 0.f; }
  int tx = tid & 31, ty = tid >> 5;
  int bRow = blockIdx.x * 64;
  float acc[8][4];
#pragma unroll
  for (int i = 0; i < 8; ++i)
#pragma unroll
    for (int j = 0; j < 4; ++j) acc[i][j] = 0.f;

  for (int k0 = 0; k0 < 512; k0 += 32) {
#pragma unroll
    for (int i = 0; i < 8; ++i) {
      int idx = i * 256 + tid;
      int r = idx >> 5, kk = idx & 31;
      int gr = bRow + r;
      XsT[kk * 68 + r] = (gr < N) ? X[(size_t)gr * 512 + k0 + kk] : 0.f;
    }
#pragma unroll
    for (int i = 0; i < 16; ++i) {
      int idx = i * 256 + tid;
      int kk = idx >> 7, j = idx & 127;
      Ws[kk * 128 + j] = Wp[(size_t)(k0 + kk) * 128 + j];
    }
    __syncthreads();
#pragma unroll 4
    for (int kk = 0; kk < 32; ++kk) {
      float4 a0 = *(const float4*)(XsT + kk * 68 + ty * 8);
      float4 a1 = *(const float4*)(XsT + kk * 68 + ty * 8 + 4);
      float4 b0 = *(const float4*)(Ws + kk * 128 + tx * 4);
      float av[8] = {a0.x, a0.y, a0.z, a0.w, a1.x, a1.y, a1.z, a1.w};
      float bv[4] = {b0.x, b0.y, b0.z, b0.w};
#pragma unroll
      for (int i = 0; i < 8; ++i)
#pragma unroll
        for (int j = 0; j < 4; ++j)
          acc[i][j] = fmaf(av[i], bv[j], acc[i][j]);
    }
    __syncthreads();
  }

  float4 bb = *(const float4*)(bp + tx * 4);
  float bv[4] = {bb.x, bb.y, bb.z, bb.w};
  float colp[4] = {0, 0, 0, 0}, colqq[4] = {0, 0, 0, 0};
#pragma unroll
  for (int i = 0; i < 8; ++i) {
    int gr = bRow + ty * 8 + i;
    if (gr < N) {
      float v[4];
#pragma unroll
      for (int j = 0; j < 4; ++j) {
        float u = fmaxf(acc[i][j] + bv[j], 0.f);
        v[j] = u;
        colp[j] += u;
        colqq[j] += u * u;
      }
      *(float4*)(Y + (size_t)gr * 128 + tx * 4) = make_float4(v[0], v[1], v[2], v[3]);
    }
  }
#pragma unroll
  for (int j = 0; j < 4; ++j) {
    atomicAdd(&csum[tx * 4 + j], colp[j]);
    atomicAdd(&cq[tx * 4 + j], colqq[j]);
  }
  __syncthreads();
  if (tid < 128) {
    atomicAdd(&s2[tid], csum[tid]);
    atomicAdd(&q2[tid], cq[tid]);
  }
}

// ---------- degree count (in-edges per dst) ----------
__global__ void k_deg(const int* __restrict__ dst, int E, int* __restrict__ deg) {
  int e = blockIdx.x * 256 + threadIdx.x;
  if (e < E) atomicAdd(&deg[dst[e]], 1);
}

// ---------- scans (CSR row offsets) ----------
__global__ __launch_bounds__(256)
void k_scan1(const int* __restrict__ deg, int N, int* __restrict__ offs,
             int* __restrict__ bsums, float* __restrict__ dinv) {
  __shared__ int sh[256];
  int t = threadIdx.x;
  int i = blockIdx.x * 256 + t;
  int c = (i < N) ? deg[i] : 0;
  if (i < N) dinv[i] = rsqrtf((float)(c + 1));
  int val = c;
  sh[t] = val;
  __syncthreads();
  for (int off = 1; off < 256; off <<= 1) {
    int add = (t >= off) ? sh[t - off] : 0;
    __syncthreads();
    val += add;
    sh[t] = val;
    __syncthreads();
  }
  if (i < N) offs[i] = val - c;
  if (t == 255) bsums[blockIdx.x] = val;
}

__global__ __launch_bounds__(256)
void k_scan2(int* __restrict__ bsums, int nb) {
  __shared__ int sh[256];
  int t = threadIdx.x;
  int v = (t < nb) ? bsums[t] : 0;
  int val = v;
  sh[t] = val;
  __syncthreads();
  for (int off = 1; off < 256; off <<= 1) {
    int add = (t >= off) ? sh[t - off] : 0;
    __syncthreads();
    val += add;
    sh[t] = val;
    __syncthreads();
  }
  if (t < nb) bsums[t] = val - v;  // exclusive
}

__global__ void k_scan3(int* __restrict__ offs, const int* __restrict__ bsums, int N) {
  int i = blockIdx.x * 256 + threadIdx.x;
  if (i < N) offs[i] += bsums[blockIdx.x];
}

// ---------- scatter src ids into CSR buckets ----------
__global__ void k_scatter(const int* __restrict__ src, const int* __restrict__ dst, int E,
                          const int* __restrict__ offs, int* __restrict__ cursor,
                          int* __restrict__ col) {
  int e = blockIdx.x * 256 + threadIdx.x;
  if (e < E) {
    int d = dst[e];
    int p = atomicAdd(&cursor[d], 1);
    col[offs[d] + p] = src[e];
  }
}

// ---------- gather: one wave per dst node ----------
__global__ __launch_bounds__(256)
void k_gather(const float* __restrict__ Y, const int* __restrict__ col,
              const int* __restrict__ offs, const int* __restrict__ deg,
              const float* __restrict__ dinv, float* __restrict__ A,
              float* __restrict__ scoef, int N) {
  int wid = threadIdx.x >> 6;
  int lane = threadIdx.x & 63;
  int d = blockIdx.x * 4 + wid;
  if (d >= N) return;
  int p = offs[d], c = deg[d];
  float dd = dinv[d];
  float2 acc;
  {
    float2 y = ((const float2*)(Y + (size_t)d * 128))[lane];
    acc.x = dd * y.x;
    acc.y = dd * y.y;
  }
  float sw = 0.f;
  for (int base = 0; base < c; base += 64) {
    int rem = c - base;
    if (rem > 64) rem = 64;
    int sidx = 0;
    float w = 0.f;
    if (lane < rem) {
      sidx = col[p + base + lane];
      w = dinv[sidx];
    }
    sw += w;
    for (int j = 0; j < rem; ++j) {
      int sj = __shfl(sidx, j);
      float wj = __shfl(w, j);
      float2 y = ((const float2*)(Y + (size_t)sj * 128))[lane];
      acc.x = fmaf(wj, y.x, acc.x);
      acc.y = fmaf(wj, y.y, acc.y);
    }
  }
#pragma unroll
  for (int off = 32; off; off >>= 1) sw += __shfl_xor(sw, off);
  ((float2*)(A + (size_t)d * 128))[lane] = make_float2(acc.x * dd, acc.y * dd);
  if (lane == 0) scoef[d] = dd * (sw + dd);
}

// ---------- final: U = A@W2p + hc*scoef + bg; relu; logits=U@Wc+bc; logsoftmax ----------
__global__ __launch_bounds__(256)
void k_final(const float* __restrict__ A, const float* __restrict__ W2p,
             const float* __restrict__ hc, const float* __restrict__ scoef,
             const float* __restrict__ bg, const float* __restrict__ Wcls,
             const float* __restrict__ bcls, float* __restrict__ out, int N) {
  __shared__ __align__(16) float Tbuf[64 * 130];  // reused: XsT[32*68] + Ws[32*128]
  __shared__ float WcS[1280];
  __shared__ float hcS[128], bgS[128], bcS[16];
  float* XsT = Tbuf;
  float* Ws = Tbuf + 2176;
  int tid = threadIdx.x;
  for (int i = tid; i < 1280; i += 256) WcS[i] = Wcls[i];
  if (tid < 128) { hcS[tid] = hc[tid]; bgS[tid] = bg[tid]; }
  if (tid < 10) bcS[tid] = bcls[tid];
  int tx = tid & 31, ty = tid >> 5;
  int bRow = blockIdx.x * 64;
  float acc[8][4];
#pragma unroll
  for (int i = 0; i < 8; ++i)
#pragma unroll
    for (int j = 0; j < 4; ++j) acc[i][j] = 0.f;

  for (int k0 = 0; k0 < 128; k0 += 32) {
#pragma unroll
    for (int i = 0; i < 8; ++i) {
      int idx = i * 256 + tid;
      int r = idx >> 5, kk = idx & 31;
      int gr = bRow + r;
      XsT[kk * 68 + r] = (gr < N) ? A[(size_t)gr * 128 + k0 + kk] : 0.f;
    }
#pragma unroll
    for (int i = 0; i < 16; ++i) {
      int idx = i * 256 + tid;
      int kk = idx >> 7, j = idx & 127;
      Ws[kk * 128 + j] = W2p[(size_t)(k0 + kk) * 128 + j];
    }
    __syncthreads();
#pragma unroll 4
    for (int kk = 0; kk < 32; ++kk) {
      float4 a0 = *(const float4*)(XsT + kk * 68 + ty * 8);
      float4 a1 = *(const float4*)(XsT + kk * 68 + ty * 8 + 4);
      float4 b0 = *(const float4*)(Ws + kk * 128 + tx * 4);
      float av[8] = {a0.x, a0.y, a0.z, a0.w, a1.x, a1.y, a1.z, a1.w};
      float bv[4] = {b0.x, b0.y, b0.z, b0.w};
#pragma unroll
      for (int i = 0; i < 8; ++i)
#pragma unroll
        for (int j = 0; j < 4; ++j)
          acc[i][j] = fmaf(av[i], bv[j], acc[i][j]);
    }
    __syncthreads();
  }

  // u + relu -> Tbuf (GEMM stage buffers are dead now; last sync done)
#pragma unroll
  for (int i = 0; i < 8; ++i) {
    int gr = bRow + ty * 8 + i;
    float sc = (gr < N) ? scoef[gr] : 0.f;
#pragma unroll
    for (int j = 0; j < 4; ++j) {
      int cc = tx * 4 + j;
      float u = acc[i][j] + hcS[cc] * sc + bgS[cc];
      Tbuf[(ty * 8 + i) * 130 + cc] = fmaxf(u, 0.f);
    }
  }
  __syncthreads();

  // classifier + log_softmax: 4 threads per row, j interleaved by 4
  int row = tid >> 2, qd = tid & 3;
  float part[10];
#pragma unroll
  for (int t = 0; t < 10; ++t) part[t] = 0.f;
  for (int jj = 0; jj < 32; ++jj) {
    int j = qd + jj * 4;
    float a = Tbuf[row * 130 + j];
#pragma unroll
    for (int t = 0; t < 10; ++t) part[t] = fmaf(a, WcS[j * 10 + t], part[t]);
  }
#pragma unroll
  for (int t = 0; t < 10; ++t) {
    part[t] += __shfl_xor(part[t], 1);
    part[t] += __shfl_xor(part[t], 2);
  }
  int gr = bRow + row;
  if (qd == 0 && gr < N) {
    float l[10], m = -1e30f;
#pragma unroll
    for (int t = 0; t < 10; ++t) {
      l[t] = part[t] + bcS[t];
      m = fmaxf(m, l[t]);
    }
    float se = 0.f;
#pragma unroll
    for (int t = 0; t < 10; ++t) se += expf(l[t] - m);
    float lse = m + logf(se);
#pragma unroll
    for (int t = 0; t < 10; ++t) out[(size_t)gr * 10 + t] = l[t] - lse;
  }
}

// ---------------------------------------------------------------------------
extern "C" void kernel_launch(void* const* d_in, const int* in_sizes, int n_in,
                              void* d_out, int out_size, void* d_ws, size_t ws_size,
                              hipStream_t stream) {
  const float* X = (const float*)d_in[0];
  // d_in[1] (low_dim_features) unused by the reference
  const int* ei = (const int*)d_in[2];
  const float* gamma1 = (const float*)d_in[3];
  const float* beta1 = (const float*)d_in[4];
  const float* Wmlp = (const float*)d_in[5];
  const float* bmlp = (const float*)d_in[6];
  const float* gamma2 = (const float*)d_in[7];
  const float* beta2 = (const float*)d_in[8];
  const float* Wgcn = (const float*)d_in[9];
  const float* bgcn = (const float*)d_in[10];
  const float* Wcls = (const float*)d_in[11];
  const float* bcls = (const float*)d_in[12];
  float* out = (float*)d_out;

  const int N = in_sizes[0] / 512;
  const int E = in_sizes[2] / 2;
  const float invN = 1.0f / (float)N;

  char* ws = (char*)d_ws;
  // ws layout (bytes)
  float* s1 = (float*)(ws + 0);            // 512
  float* q1 = (float*)(ws + 2048);         // 512
  float* s2 = (float*)(ws + 4096);         // 128
  float* q2 = (float*)(ws + 4608);         // 128
  float* b1p = (float*)(ws + 5120);        // 128
  float* hconst = (float*)(ws + 5632);     // 128
  float* W1p = (float*)(ws + 8192);        // 512*128
  float* W2p = (float*)(ws + 270336);      // 128*128
  int* deg = (int*)(ws + 335872);          // N
  int* cursor = (int*)(ws + 535872);       // N
  int* offs = (int*)(ws + 735872);         // N
  float* dinv = (float*)(ws + 935872);     // N
  int* bsums = (int*)(ws + 1135872);       // 256
  float* scoef = (float*)(ws + 1136896);   // N
  float* Y = (float*)(ws + 1337344);       // N*128
  float* A = (float*)(ws + 26937344);      // N*128
  int* col = (int*)(ws + 52537344);        // E
  (void)ws_size; (void)n_in; (void)out_size;

  const int* esrc = ei;
  const int* edst = ei + E;
  int nb = (N + 255) / 256;          // 196
  int eb = (E + 255) / 256;          // 3125
  int gb = (N + 63) / 64;            // 782

  // zero accumulators (s1,q1,s2,q2 = 1280 floats) and deg+cursor (2N ints)
  k_zero<<<5, 256, 0, stream>>>((float*)(ws + 0), 1280);
  k_zero<<<(2 * N + 255) / 256, 256, 0, stream>>>((float*)(ws + 335872), 2 * N);

  k_bn1_stats<<<512, 512, 0, stream>>>(X, N, s1, q1);
  k_foldw<<<256, 256, 0, stream>>>(s1, q1, gamma1, beta1, Wmlp, W1p, invN);
  k_foldb<<<1, 128, 0, stream>>>(s1, q1, gamma1, beta1, Wmlp, bmlp, b1p, invN, 512);
  k_gemm1<<<gb, 256, 0, stream>>>(X, W1p, b1p, Y, s2, q2, N);

  k_deg<<<eb, 256, 0, stream>>>(edst, E, deg);
  k_scan1<<<nb, 256, 0, stream>>>(deg, N, offs, bsums, dinv);
  k_scan2<<<1, 256, 0, stream>>>(bsums, nb);
  k_scan3<<<nb, 256, 0, stream>>>(offs, bsums, N);
  k_scatter<<<eb, 256, 0, stream>>>(esrc, edst, E, offs, cursor, col);

  k_foldw<<<64, 256, 0, stream>>>(s2, q2, gamma2, beta2, Wgcn, W2p, invN);
  k_foldb<<<1, 128, 0, stream>>>(s2, q2, gamma2, beta2, Wgcn, nullptr, hconst, invN, 128);

  k_gather<<<(N + 3) / 4, 256, 0, stream>>>(Y, col, offs, deg, dinv, A, scoef, N);
  k_final<<<gb, 256, 0, stream>>>(A, W2p, hconst, scoef, bgcn, Wcls, bcls, out, N);
}

// Round 2
// 354.198 us; speedup vs baseline: 1.4940x; 1.4940x over previous
//
#include <hip/hip_runtime.h>
#include <math.h>

#define EPS 1e-5f

typedef short short8 __attribute__((ext_vector_type(8)));
typedef float f32x4 __attribute__((ext_vector_type(4)));
typedef unsigned short u16;

__device__ inline u16 f2bf(float f) {
  union { float f; unsigned u; } x; x.f = f;
  return (u16)((x.u + 0x7fffu + ((x.u >> 16) & 1u)) >> 16);
}
__device__ inline float bf2f(u16 h) {
  union { float f; unsigned u; } x; x.u = ((unsigned)h) << 16;
  return x.f;
}

__device__ inline void gload_lds16(const void* g, void* l) {
  __builtin_amdgcn_global_load_lds((const __attribute__((address_space(1))) void*)g,
                                   (__attribute__((address_space(3))) void*)l, 16, 0, 0);
}

__global__ void k_zero(float* __restrict__ p, int n) {
  int i = blockIdx.x * 256 + threadIdx.x;
  if (i < n) p[i] = 0.f;
}

// ---------- BN1 column stats over X [N,512] ----------
__global__ __launch_bounds__(512)
void k_bn1_stats(const float* __restrict__ X, int N,
                 float* __restrict__ s, float* __restrict__ q) {
  int c = threadIdx.x;
  float sum = 0.f, sq = 0.f;
  for (int r = blockIdx.x; r < N; r += gridDim.x) {
    float v = X[(size_t)r * 512 + c];
    sum += v;
    sq += v * v;
  }
  atomicAdd(&s[c], sum);
  atomicAdd(&q[c], sq);
}

// ---------- fold BN scale into TRANSPOSED bf16 weights: WT[j][k] = a[k]*W[k][j] ----------
__global__ void k_foldwT(const float* __restrict__ s, const float* __restrict__ q,
                         const float* __restrict__ gamma,
                         const float* __restrict__ W, u16* __restrict__ WT,
                         float invN, int lgK) {
  int idx = blockIdx.x * 256 + threadIdx.x;
  int K = 1 << lgK;
  int j = idx >> lgK, k = idx & (K - 1);
  float mu = s[k] * invN;
  float var = fmaxf(q[k] * invN - mu * mu, 0.f);
  float a = gamma[k] * rsqrtf(var + EPS);
  WT[idx] = f2bf(a * W[(size_t)k * 128 + j]);
}

// ---------- fold BN shift: bp[j] = (b?b[j]:0) + sum_k c[k]*W[k][j] ----------
__global__ void k_foldb(const float* __restrict__ s, const float* __restrict__ q,
                        const float* __restrict__ gamma, const float* __restrict__ beta,
                        const float* __restrict__ W, const float* __restrict__ b,
                        float* __restrict__ bp, float invN, int K) {
  int j = threadIdx.x;  // 0..127
  float acc = b ? b[j] : 0.f;
  for (int k = 0; k < K; ++k) {
    float mu = s[k] * invN;
    float var = fmaxf(q[k] * invN - mu * mu, 0.f);
    float a = gamma[k] * rsqrtf(var + EPS);
    float c = beta[k] - mu * a;
    acc += c * W[k * 128 + j];
  }
  bp[j] = acc;
}

// ---------- GEMM1 (MFMA bf16): Yb = relu(X@W1p + bp) as bf16; col stats of Y ----------
// 128x128 tile, BK=64, 2x2 waves of 64x64. A: reg-staged fp32->bf16 with XOR
// swizzle. B: W1bT[j][k] via global_load_lds with pre-swizzled source.
__global__ __launch_bounds__(256)
void k_gemm1(const float* __restrict__ X, const u16* __restrict__ WT,
             const float* __restrict__ bp, u16* __restrict__ Yb,
             float* __restrict__ s2, float* __restrict__ q2, int N) {
  __shared__ __align__(16) u16 As[128 * 64];
  __shared__ __align__(16) u16 Bs[128 * 64];
  __shared__ float csum[128], cq[128];
  int tid = threadIdx.x;
  if (tid < 128) { csum[tid] = 0.f; cq[tid] = 0.f; }
  int lane = tid & 63, wid = tid >> 6;
  int wm = wid & 1, wn = wid >> 1;
  int bRow = blockIdx.x * 128;

  f32x4 acc[4][4];
#pragma unroll
  for (int mi = 0; mi < 4; ++mi)
#pragma unroll
    for (int ni = 0; ni < 4; ++ni) acc[mi][ni] = {0.f, 0.f, 0.f, 0.f};

  for (int k0 = 0; k0 < 512; k0 += 64) {
    // A: global fp32 loads into regs (issue before barrier to overlap)
    float4 ar[4][2];
#pragma unroll
    for (int i = 0; i < 4; ++i) {
      int p = i * 256 + tid;
      int row = p >> 3, slot = p & 7, srs = slot ^ (row & 7);
      int gr = bRow + row; if (gr >= N) gr = N - 1;
      const float4* g = (const float4*)(X + (size_t)gr * 512 + (k0 + srs * 8));
      ar[i][0] = g[0];
      ar[i][1] = g[1];
    }
    __syncthreads();  // previous iteration's LDS readers done
    // B: async global->LDS (source pre-swizzled so linear LDS dest + swz read match)
#pragma unroll
    for (int i = 0; i < 4; ++i) {
      int p = i * 256 + tid;
      int row = p >> 3, slot = p & 7, srs = slot ^ (row & 7);
      gload_lds16(WT + (size_t)row * 512 + (k0 + srs * 8), (char*)Bs + p * 16);
    }
    // A: convert + swizzled ds_write_b128
#pragma unroll
    for (int i = 0; i < 4; ++i) {
      int p = i * 256 + tid;
      const float* f0 = (const float*)&ar[i][0];
      short8 v;
#pragma unroll
      for (int j = 0; j < 8; ++j) v[j] = (short)f2bf(f0[j]);
      *(short8*)((char*)As + p * 16) = v;
    }
    __syncthreads();  // drains vmcnt for gload_lds + lgkmcnt for ds_write
#pragma unroll
    for (int ks = 0; ks < 2; ++ks) {
      short8 af[4], bfv[4];
#pragma unroll
      for (int mi = 0; mi < 4; ++mi) {
        int row = wm * 64 + mi * 16 + (lane & 15);
        int swz = (ks * 4 + (lane >> 4)) ^ (lane & 7);
        af[mi] = *(const short8*)(As + row * 64 + swz * 8);
      }
#pragma unroll
      for (int ni = 0; ni < 4; ++ni) {
        int row = wn * 64 + ni * 16 + (lane & 15);
        int swz = (ks * 4 + (lane >> 4)) ^ (lane & 7);
        bfv[ni] = *(const short8*)(Bs + row * 64 + swz * 8);
      }
#pragma unroll
      for (int mi = 0; mi < 4; ++mi)
#pragma unroll
        for (int ni = 0; ni < 4; ++ni)
          acc[mi][ni] = __builtin_amdgcn_mfma_f32_16x16x32_bf16(af[mi], bfv[ni], acc[mi][ni], 0, 0, 0);
    }
  }

  // epilogue: bias, relu, bf16 store, column stats
  float bias[4];
#pragma unroll
  for (int ni = 0; ni < 4; ++ni) bias[ni] = bp[wn * 64 + ni * 16 + (lane & 15)];
  float colp[4] = {0, 0, 0, 0}, colq[4] = {0, 0, 0, 0};
#pragma unroll
  for (int mi = 0; mi < 4; ++mi) {
#pragma unroll
    for (int r = 0; r < 4; ++r) {
      int gr = bRow + wm * 64 + mi * 16 + (lane >> 4) * 4 + r;
      if (gr < N) {
#pragma unroll
        for (int ni = 0; ni < 4; ++ni) {
          float u = fmaxf(acc[mi][ni][r] + bias[ni], 0.f);
          colp[ni] += u;
          colq[ni] += u * u;
          Yb[(size_t)gr * 128 + wn * 64 + ni * 16 + (lane & 15)] = f2bf(u);
        }
      }
    }
  }
#pragma unroll
  for (int ni = 0; ni < 4; ++ni) {
    float a = colp[ni], b = colq[ni];
    a += __shfl_xor(a, 16); a += __shfl_xor(a, 32);
    b += __shfl_xor(b, 16); b += __shfl_xor(b, 32);
    if (lane < 16) {
      atomicAdd(&csum[wn * 64 + ni * 16 + lane], a);
      atomicAdd(&cq[wn * 64 + ni * 16 + lane], b);
    }
  }
  __syncthreads();
  if (tid < 128) {
    atomicAdd(&s2[tid], csum[tid]);
    atomicAdd(&q2[tid], cq[tid]);
  }
}

// ---------- degree count ----------
__global__ void k_deg(const int* __restrict__ dst, int E, int* __restrict__ deg) {
  int e = blockIdx.x * 256 + threadIdx.x;
  if (e < E) atomicAdd(&deg[dst[e]], 1);
}

// ---------- scans ----------
__global__ __launch_bounds__(256)
void k_scan1(const int* __restrict__ deg, int N, int* __restrict__ offs,
             int* __restrict__ bsums, float* __restrict__ dinv) {
  __shared__ int sh[256];
  int t = threadIdx.x;
  int i = blockIdx.x * 256 + t;
  int c = (i < N) ? deg[i] : 0;
  if (i < N) dinv[i] = rsqrtf((float)(c + 1));
  int val = c;
  sh[t] = val;
  __syncthreads();
  for (int off = 1; off < 256; off <<= 1) {
    int add = (t >= off) ? sh[t - off] : 0;
    __syncthreads();
    val += add;
    sh[t] = val;
    __syncthreads();
  }
  if (i < N) offs[i] = val - c;
  if (t == 255) bsums[blockIdx.x] = val;
}

__global__ __launch_bounds__(256)
void k_scan2(int* __restrict__ bsums, int nb) {
  __shared__ int sh[256];
  int t = threadIdx.x;
  int v = (t < nb) ? bsums[t] : 0;
  int val = v;
  sh[t] = val;
  __syncthreads();
  for (int off = 1; off < 256; off <<= 1) {
    int add = (t >= off) ? sh[t - off] : 0;
    __syncthreads();
    val += add;
    sh[t] = val;
    __syncthreads();
  }
  if (t < nb) bsums[t] = val - v;
}

__global__ void k_scan3(int* __restrict__ offs, const int* __restrict__ bsums, int N) {
  int i = blockIdx.x * 256 + threadIdx.x;
  if (i < N) offs[i] += bsums[blockIdx.x];
}

// ---------- scatter src ids into CSR buckets ----------
__global__ void k_scatter(const int* __restrict__ src, const int* __restrict__ dst, int E,
                          const int* __restrict__ offs, int* __restrict__ cursor,
                          int* __restrict__ col) {
  int e = blockIdx.x * 256 + threadIdx.x;
  if (e < E) {
    int d = dst[e];
    int p = atomicAdd(&cursor[d], 1);
    col[offs[d] + p] = src[e];
  }
}

// ---------- gather (bf16 Y -> bf16 A): one wave per dst node ----------
__global__ __launch_bounds__(256)
void k_gather(const u16* __restrict__ Yb, const int* __restrict__ col,
              const int* __restrict__ offs, const int* __restrict__ deg,
              const float* __restrict__ dinv, u16* __restrict__ Ab,
              float* __restrict__ scoef, int N) {
  int wid = threadIdx.x >> 6;
  int lane = threadIdx.x & 63;
  int d = blockIdx.x * 4 + wid;
  if (d >= N) return;
  int p = offs[d], c = deg[d];
  float dd = dinv[d];
  float ax, ay;
  {
    unsigned v = ((const unsigned*)(Yb + (size_t)d * 128))[lane];
    ax = dd * bf2f((u16)v);
    ay = dd * bf2f((u16)(v >> 16));
  }
  float sw = 0.f;
  for (int base = 0; base < c; base += 64) {
    int rem = c - base;
    if (rem > 64) rem = 64;
    int sidx = 0;
    float w = 0.f;
    if (lane < rem) {
      sidx = col[p + base + lane];
      w = dinv[sidx];
    }
    sw += w;
    for (int j = 0; j < rem; ++j) {
      int sj = __shfl(sidx, j);
      float wj = __shfl(w, j);
      unsigned v = ((const unsigned*)(Yb + (size_t)sj * 128))[lane];
      ax = fmaf(wj, bf2f((u16)v), ax);
      ay = fmaf(wj, bf2f((u16)(v >> 16)), ay);
    }
  }
#pragma unroll
  for (int off = 32; off; off >>= 1) sw += __shfl_xor(sw, off);
  unsigned o = (unsigned)f2bf(ax * dd) | ((unsigned)f2bf(ay * dd) << 16);
  ((unsigned*)(Ab + (size_t)d * 128))[lane] = o;
  if (lane == 0) scoef[d] = dd * (sw + dd);
}

// ---------- final (MFMA bf16, BK=128 single pass) ----------
__global__ __launch_bounds__(256)
void k_final(const u16* __restrict__ Ab, const u16* __restrict__ W2T,
             const float* __restrict__ hc, const float* __restrict__ scoef,
             const float* __restrict__ bg, const float* __restrict__ Wcls,
             const float* __restrict__ bcls, float* __restrict__ out, int N) {
  __shared__ __align__(16) char smem[65536];
  __shared__ float WcS[1280];
  __shared__ float hcS[128], bgS[128], bcS[10];
  u16* As = (u16*)smem;            // [128 rows][128 k] swizzled, 32KB
  u16* Bs = (u16*)(smem + 32768);  // [128 cols][128 k] swizzled, 32KB
  u16* Tb = (u16*)smem;            // reused after compute: [128][136] bf16
  int tid = threadIdx.x;
  for (int i = tid; i < 1280; i += 256) WcS[i] = Wcls[i];
  if (tid < 128) { hcS[tid] = hc[tid]; bgS[tid] = bg[tid]; }
  if (tid < 10) bcS[tid] = bcls[tid];
  int lane = tid & 63, wid = tid >> 6;
  int wm = wid & 1, wn = wid >> 1;
  int bRow = blockIdx.x * 128;

  // stage A and B tiles (whole K=128)
#pragma unroll
  for (int i = 0; i < 8; ++i) {
    int p = i * 256 + tid;
    int row = p >> 4, slot = p & 15, srs = slot ^ (row & 7);
    int gr = bRow + row; if (gr >= N) gr = N - 1;
    gload_lds16(Ab + (size_t)gr * 128 + srs * 8, (char*)As + p * 16);
    gload_lds16(W2T + (size_t)row * 128 + srs * 8, (char*)Bs + p * 16);
  }
  f32x4 acc[4][4];
#pragma unroll
  for (int mi = 0; mi < 4; ++mi)
#pragma unroll
    for (int ni = 0; ni < 4; ++ni) acc[mi][ni] = {0.f, 0.f, 0.f, 0.f};
  __syncthreads();
#pragma unroll
  for (int ks = 0; ks < 4; ++ks) {
    short8 af[4], bfv[4];
#pragma unroll
    for (int mi = 0; mi < 4; ++mi) {
      int row = wm * 64 + mi * 16 + (lane & 15);
      int swz = (ks * 4 + (lane >> 4)) ^ (lane & 7);
      af[mi] = *(const short8*)(As + row * 128 + swz * 8);
    }
#pragma unroll
    for (int ni = 0; ni < 4; ++ni) {
      int row = wn * 64 + ni * 16 + (lane & 15);
      int swz = (ks * 4 + (lane >> 4)) ^ (lane & 7);
      bfv[ni] = *(const short8*)(Bs + row * 128 + swz * 8);
    }
#pragma unroll
    for (int mi = 0; mi < 4; ++mi)
#pragma unroll
      for (int ni = 0; ni < 4; ++ni)
        acc[mi][ni] = __builtin_amdgcn_mfma_f32_16x16x32_bf16(af[mi], bfv[ni], acc[mi][ni], 0, 0, 0);
  }
  __syncthreads();  // all LDS reads done before Tb overwrite

  // epilogue: u = acc + hc*scoef + bg, relu -> Tb (bf16)
  float hcv[4], bgv[4];
#pragma unroll
  for (int ni = 0; ni < 4; ++ni) {
    int n = wn * 64 + ni * 16 + (lane & 15);
    hcv[ni] = hcS[n];
    bgv[ni] = bgS[n];
  }
#pragma unroll
  for (int mi = 0; mi < 4; ++mi) {
#pragma unroll
    for (int r = 0; r < 4; ++r) {
      int m = wm * 64 + mi * 16 + (lane >> 4) * 4 + r;
      int gr = bRow + m;
      float sc = (gr < N) ? scoef[gr] : 0.f;
#pragma unroll
      for (int ni = 0; ni < 4; ++ni) {
        float u = fmaxf(acc[mi][ni][r] + hcv[ni] * sc + bgv[ni], 0.f);
        Tb[m * 136 + wn * 64 + ni * 16 + (lane & 15)] = f2bf(u);
      }
    }
  }
  __syncthreads();

  // classifier + log_softmax: 2 threads per row
  int r2 = tid >> 1, qd = tid & 1;
  float part[10];
#pragma unroll
  for (int t = 0; t < 10; ++t) part[t] = 0.f;
  for (int jj = 0; jj < 64; ++jj) {
    int j = qd * 64 + jj;
    float a = bf2f(Tb[r2 * 136 + j]);
#pragma unroll
    for (int t = 0; t < 10; ++t) part[t] = fmaf(a, WcS[j * 10 + t], part[t]);
  }
#pragma unroll
  for (int t = 0; t < 10; ++t) part[t] += __shfl_xor(part[t], 1);
  int gr = bRow + r2;
  if (qd == 0 && gr < N) {
    float l[10], m = -1e30f;
#pragma unroll
    for (int t = 0; t < 10; ++t) {
      l[t] = part[t] + bcS[t];
      m = fmaxf(m, l[t]);
    }
    float se = 0.f;
#pragma unroll
    for (int t = 0; t < 10; ++t) se += expf(l[t] - m);
    float lse = m + logf(se);
#pragma unroll
    for (int t = 0; t < 10; ++t) out[(size_t)gr * 10 + t] = l[t] - lse;
  }
}

// ---------------------------------------------------------------------------
extern "C" void kernel_launch(void* const* d_in, const int* in_sizes, int n_in,
                              void* d_out, int out_size, void* d_ws, size_t ws_size,
                              hipStream_t stream) {
  const float* X = (const float*)d_in[0];
  const int* ei = (const int*)d_in[2];
  const float* gamma1 = (const float*)d_in[3];
  const float* beta1 = (const float*)d_in[4];
  const float* Wmlp = (const float*)d_in[5];
  const float* bmlp = (const float*)d_in[6];
  const float* gamma2 = (const float*)d_in[7];
  const float* beta2 = (const float*)d_in[8];
  const float* Wgcn = (const float*)d_in[9];
  const float* bgcn = (const float*)d_in[10];
  const float* Wcls = (const float*)d_in[11];
  const float* bcls = (const float*)d_in[12];
  float* out = (float*)d_out;

  const int N = in_sizes[0] / 512;
  const int E = in_sizes[2] / 2;
  const float invN = 1.0f / (float)N;

  char* ws = (char*)d_ws;
  float* s1 = (float*)(ws + 0);            // 512
  float* q1 = (float*)(ws + 2048);         // 512
  float* s2 = (float*)(ws + 4096);         // 128
  float* q2 = (float*)(ws + 4608);         // 128
  float* b1p = (float*)(ws + 5120);        // 128
  float* hconst = (float*)(ws + 5632);     // 128
  u16* W1bT = (u16*)(ws + 8192);           // 128*512 bf16 -> ends 139264
  u16* W2bT = (u16*)(ws + 139264);         // 128*128 bf16 -> ends 172032
  int* bsums = (int*)(ws + 172032);        // 256 -> 173056
  int* deg = (int*)(ws + 173056);          // N
  int* cursor = (int*)(ws + 373056);       // N
  int* offs = (int*)(ws + 573056);         // N
  float* dinv = (float*)(ws + 773056);     // N
  float* scoef = (float*)(ws + 973056);    // N
  int* col = (int*)(ws + 1173056);         // E -> 4373056
  u16* Yb = (u16*)(ws + 4373504);          // N*128 bf16 -> 17173504
  u16* Ab = (u16*)(ws + 17173504);         // N*128 bf16 -> 29973504
  (void)ws_size; (void)n_in; (void)out_size;

  const int* esrc = ei;
  const int* edst = ei + E;
  int nb = (N + 255) / 256;
  int eb = (E + 255) / 256;
  int gb = (N + 127) / 128;  // 391

  k_zero<<<5, 256, 0, stream>>>(s1, 1280);
  k_zero<<<(2 * N + 255) / 256, 256, 0, stream>>>((float*)deg, 2 * N);

  k_bn1_stats<<<1024, 512, 0, stream>>>(X, N, s1, q1);
  k_foldwT<<<256, 256, 0, stream>>>(s1, q1, gamma1, Wmlp, W1bT, invN, 9);
  k_foldb<<<1, 128, 0, stream>>>(s1, q1, gamma1, beta1, Wmlp, bmlp, b1p, invN, 512);
  k_gemm1<<<gb, 256, 0, stream>>>(X, W1bT, b1p, Yb, s2, q2, N);

  k_deg<<<eb, 256, 0, stream>>>(edst, E, deg);
  k_scan1<<<nb, 256, 0, stream>>>(deg, N, offs, bsums, dinv);
  k_scan2<<<1, 256, 0, stream>>>(bsums, nb);
  k_scan3<<<nb, 256, 0, stream>>>(offs, bsums, N);
  k_scatter<<<eb, 256, 0, stream>>>(esrc, edst, E, offs, cursor, col);

  k_foldwT<<<64, 256, 0, stream>>>(s2, q2, gamma2, Wgcn, W2bT, invN, 7);
  k_foldb<<<1, 128, 0, stream>>>(s2, q2, gamma2, beta2, Wgcn, nullptr, hconst, invN, 128);

  k_gather<<<(N + 3) / 4, 256, 0, stream>>>(Yb, col, offs, deg, dinv, Ab, scoef, N);
  k_final<<<gb, 256, 0, stream>>>(Ab, W2bT, hconst, scoef, bgcn, Wcls, bcls, out, N);
}

// Round 3
// 251.755 us; speedup vs baseline: 2.1019x; 1.4069x over previous
//
#include <hip/hip_runtime.h>
#include <math.h>

#define EPS 1e-5f

typedef short short8 __attribute__((ext_vector_type(8)));
typedef float f32x4 __attribute__((ext_vector_type(4)));
typedef unsigned short u16;

__device__ inline u16 f2bf(float f) {
  union { float f; unsigned u; } x; x.f = f;
  return (u16)((x.u + 0x7fffu + ((x.u >> 16) & 1u)) >> 16);
}
__device__ inline float bf2f(u16 h) {
  union { float f; unsigned u; } x; x.u = ((unsigned)h) << 16;
  return x.f;
}

__device__ inline void gload_lds16(const void* g, void* l) {
  __builtin_amdgcn_global_load_lds((const __attribute__((address_space(1))) void*)g,
                                   (__attribute__((address_space(3))) void*)l, 16, 0, 0);
}

__global__ void k_zero(float* __restrict__ p, int n) {
  int i = blockIdx.x * 256 + threadIdx.x;
  if (i < n) p[i] = 0.f;
}

// ---------- BN1 column stats over X [N,512] ----------
__global__ __launch_bounds__(512)
void k_bn1_stats(const float* __restrict__ X, int N,
                 float* __restrict__ s, float* __restrict__ q) {
  int c = threadIdx.x;
  float sum = 0.f, sq = 0.f;
  for (int r = blockIdx.x; r < N; r += gridDim.x) {
    float v = X[(size_t)r * 512 + c];
    sum += v;
    sq += v * v;
  }
  atomicAdd(&s[c], sum);
  atomicAdd(&q[c], sq);
}

// ---------- fold BN scale into TRANSPOSED bf16 weights: WT[j][k] = a[k]*W[k][j] ----------
__global__ void k_foldwT(const float* __restrict__ s, const float* __restrict__ q,
                         const float* __restrict__ gamma,
                         const float* __restrict__ W, u16* __restrict__ WT,
                         float invN, int lgK) {
  int idx = blockIdx.x * 256 + threadIdx.x;
  int K = 1 << lgK;
  int j = idx >> lgK, k = idx & (K - 1);
  float mu = s[k] * invN;
  float var = fmaxf(q[k] * invN - mu * mu, 0.f);
  float a = gamma[k] * rsqrtf(var + EPS);
  WT[idx] = f2bf(a * W[(size_t)k * 128 + j]);
}

// ---------- parallel fold BN shift: bp[j] += sum_k c[k]*W[k][j] (split-K, atomic) ----------
// grid.x blocks each cover kPerBlock k's; block = (2 k-slots x 128 j). bp pre-zeroed.
__global__ __launch_bounds__(256)
void k_foldb_par(const float* __restrict__ s, const float* __restrict__ q,
                 const float* __restrict__ gamma, const float* __restrict__ beta,
                 const float* __restrict__ W, const float* __restrict__ b,
                 float* __restrict__ bp, float invN, int kPerBlock) {
  __shared__ float sh[256];
  int j = threadIdx.x & 127;
  int ksub = threadIdx.x >> 7;  // 0..1
  int k0 = blockIdx.x * kPerBlock;
  float acc = 0.f;
  for (int k = k0 + ksub; k < k0 + kPerBlock; k += 2) {
    float mu = s[k] * invN;
    float var = fmaxf(q[k] * invN - mu * mu, 0.f);
    float a = gamma[k] * rsqrtf(var + EPS);
    float c = beta[k] - mu * a;
    acc = fmaf(c, W[(size_t)k * 128 + j], acc);
  }
  sh[threadIdx.x] = acc;
  __syncthreads();
  if (threadIdx.x < 128) {
    float v = sh[threadIdx.x] + sh[threadIdx.x + 128];
    if (blockIdx.x == 0) v += (b ? b[j] : 0.f);
    atomicAdd(&bp[j], v);
  }
}

// ---------- GEMM1 (MFMA bf16): Yb = relu(X@W1p + bp) as bf16; col stats of Y ----------
__global__ __launch_bounds__(256)
void k_gemm1(const float* __restrict__ X, const u16* __restrict__ WT,
             const float* __restrict__ bp, u16* __restrict__ Yb,
             float* __restrict__ s2, float* __restrict__ q2, int N) {
  __shared__ __align__(16) u16 As[128 * 64];
  __shared__ __align__(16) u16 Bs[128 * 64];
  __shared__ float csum[128], cq[128];
  int tid = threadIdx.x;
  if (tid < 128) { csum[tid] = 0.f; cq[tid] = 0.f; }
  int lane = tid & 63, wid = tid >> 6;
  int wm = wid & 1, wn = wid >> 1;
  int bRow = blockIdx.x * 128;

  f32x4 acc[4][4];
#pragma unroll
  for (int mi = 0; mi < 4; ++mi)
#pragma unroll
    for (int ni = 0; ni < 4; ++ni) acc[mi][ni] = {0.f, 0.f, 0.f, 0.f};

  for (int k0 = 0; k0 < 512; k0 += 64) {
    // A: global fp32 loads into regs (issue before barrier to overlap)
    float4 ar[4][2];
#pragma unroll
    for (int i = 0; i < 4; ++i) {
      int p = i * 256 + tid;
      int row = p >> 3, slot = p & 7, srs = slot ^ (row & 7);
      int gr = bRow + row; if (gr >= N) gr = N - 1;
      const float4* g = (const float4*)(X + (size_t)gr * 512 + (k0 + srs * 8));
      ar[i][0] = g[0];
      ar[i][1] = g[1];
    }
    __syncthreads();  // previous iteration's LDS readers done
    // B: async global->LDS (source pre-swizzled so linear LDS dest + swz read match)
#pragma unroll
    for (int i = 0; i < 4; ++i) {
      int p = i * 256 + tid;
      int row = p >> 3, slot = p & 7, srs = slot ^ (row & 7);
      gload_lds16(WT + (size_t)row * 512 + (k0 + srs * 8), (char*)Bs + p * 16);
    }
    // A: convert + swizzled ds_write_b128
#pragma unroll
    for (int i = 0; i < 4; ++i) {
      int p = i * 256 + tid;
      const float* f0 = (const float*)&ar[i][0];
      short8 v;
#pragma unroll
      for (int j = 0; j < 8; ++j) v[j] = (short)f2bf(f0[j]);
      *(short8*)((char*)As + p * 16) = v;
    }
    __syncthreads();  // drains vmcnt for gload_lds + lgkmcnt for ds_write
#pragma unroll
    for (int ks = 0; ks < 2; ++ks) {
      short8 af[4], bfv[4];
#pragma unroll
      for (int mi = 0; mi < 4; ++mi) {
        int row = wm * 64 + mi * 16 + (lane & 15);
        int swz = (ks * 4 + (lane >> 4)) ^ (lane & 7);
        af[mi] = *(const short8*)(As + row * 64 + swz * 8);
      }
#pragma unroll
      for (int ni = 0; ni < 4; ++ni) {
        int row = wn * 64 + ni * 16 + (lane & 15);
        int swz = (ks * 4 + (lane >> 4)) ^ (lane & 7);
        bfv[ni] = *(const short8*)(Bs + row * 64 + swz * 8);
      }
#pragma unroll
      for (int mi = 0; mi < 4; ++mi)
#pragma unroll
        for (int ni = 0; ni < 4; ++ni)
          acc[mi][ni] = __builtin_amdgcn_mfma_f32_16x16x32_bf16(af[mi], bfv[ni], acc[mi][ni], 0, 0, 0);
    }
  }

  // epilogue: bias, relu, bf16 store, column stats
  float bias[4];
#pragma unroll
  for (int ni = 0; ni < 4; ++ni) bias[ni] = bp[wn * 64 + ni * 16 + (lane & 15)];
  float colp[4] = {0, 0, 0, 0}, colq[4] = {0, 0, 0, 0};
#pragma unroll
  for (int mi = 0; mi < 4; ++mi) {
#pragma unroll
    for (int r = 0; r < 4; ++r) {
      int gr = bRow + wm * 64 + mi * 16 + (lane >> 4) * 4 + r;
      if (gr < N) {
#pragma unroll
        for (int ni = 0; ni < 4; ++ni) {
          float u = fmaxf(acc[mi][ni][r] + bias[ni], 0.f);
          colp[ni] += u;
          colq[ni] += u * u;
          Yb[(size_t)gr * 128 + wn * 64 + ni * 16 + (lane & 15)] = f2bf(u);
        }
      }
    }
  }
#pragma unroll
  for (int ni = 0; ni < 4; ++ni) {
    float a = colp[ni], b = colq[ni];
    a += __shfl_xor(a, 16); a += __shfl_xor(a, 32);
    b += __shfl_xor(b, 16); b += __shfl_xor(b, 32);
    if (lane < 16) {
      atomicAdd(&csum[wn * 64 + ni * 16 + lane], a);
      atomicAdd(&cq[wn * 64 + ni * 16 + lane], b);
    }
  }
  __syncthreads();
  if (tid < 128) {
    atomicAdd(&s2[tid], csum[tid]);
    atomicAdd(&q2[tid], cq[tid]);
  }
}

// ---------- degree count ----------
__global__ void k_deg(const int* __restrict__ dst, int E, int* __restrict__ deg) {
  int e = blockIdx.x * 256 + threadIdx.x;
  if (e < E) atomicAdd(&deg[dst[e]], 1);
}

// ---------- scans ----------
__global__ __launch_bounds__(256)
void k_scan1(const int* __restrict__ deg, int N, int* __restrict__ offs,
             int* __restrict__ bsums, float* __restrict__ dinv) {
  __shared__ int sh[256];
  int t = threadIdx.x;
  int i = blockIdx.x * 256 + t;
  int c = (i < N) ? deg[i] : 0;
  if (i < N) dinv[i] = rsqrtf((float)(c + 1));
  int val = c;
  sh[t] = val;
  __syncthreads();
  for (int off = 1; off < 256; off <<= 1) {
    int add = (t >= off) ? sh[t - off] : 0;
    __syncthreads();
    val += add;
    sh[t] = val;
    __syncthreads();
  }
  if (i < N) offs[i] = val - c;
  if (t == 255) bsums[blockIdx.x] = val;
}

__global__ __launch_bounds__(256)
void k_scan2(int* __restrict__ bsums, int nb) {
  __shared__ int sh[256];
  int t = threadIdx.x;
  int v = (t < nb) ? bsums[t] : 0;
  int val = v;
  sh[t] = val;
  __syncthreads();
  for (int off = 1; off < 256; off <<= 1) {
    int add = (t >= off) ? sh[t - off] : 0;
    __syncthreads();
    val += add;
    sh[t] = val;
    __syncthreads();
  }
  if (t < nb) bsums[t] = val - v;
}

__global__ void k_scan3(int* __restrict__ offs, const int* __restrict__ bsums, int N) {
  int i = blockIdx.x * 256 + threadIdx.x;
  if (i < N) offs[i] += bsums[blockIdx.x];
}

// ---------- scatter src ids into CSR buckets ----------
__global__ void k_scatter(const int* __restrict__ src, const int* __restrict__ dst, int E,
                          const int* __restrict__ offs, int* __restrict__ cursor,
                          int* __restrict__ col) {
  int e = blockIdx.x * 256 + threadIdx.x;
  if (e < E) {
    int d = dst[e];
    int p = atomicAdd(&cursor[d], 1);
    col[offs[d] + p] = src[e];
  }
}

// ---------- gather (bf16 Y -> bf16 A): one wave per dst node ----------
__global__ __launch_bounds__(256)
void k_gather(const u16* __restrict__ Yb, const int* __restrict__ col,
              const int* __restrict__ offs, const int* __restrict__ deg,
              const float* __restrict__ dinv, u16* __restrict__ Ab,
              float* __restrict__ scoef, int N) {
  int wid = threadIdx.x >> 6;
  int lane = threadIdx.x & 63;
  int d = blockIdx.x * 4 + wid;
  if (d >= N) return;
  int p = offs[d], c = deg[d];
  float dd = dinv[d];
  float ax, ay;
  {
    unsigned v = ((const unsigned*)(Yb + (size_t)d * 128))[lane];
    ax = dd * bf2f((u16)v);
    ay = dd * bf2f((u16)(v >> 16));
  }
  float sw = 0.f;
  for (int base = 0; base < c; base += 64) {
    int rem = c - base;
    if (rem > 64) rem = 64;
    int sidx = 0;
    float w = 0.f;
    if (lane < rem) {
      sidx = col[p + base + lane];
      w = dinv[sidx];
    }
    sw += w;
    for (int j = 0; j < rem; ++j) {
      int sj = __shfl(sidx, j);
      float wj = __shfl(w, j);
      unsigned v = ((const unsigned*)(Yb + (size_t)sj * 128))[lane];
      ax = fmaf(wj, bf2f((u16)v), ax);
      ay = fmaf(wj, bf2f((u16)(v >> 16)), ay);
    }
  }
#pragma unroll
  for (int off = 32; off; off >>= 1) sw += __shfl_xor(sw, off);
  unsigned o = (unsigned)f2bf(ax * dd) | ((unsigned)f2bf(ay * dd) << 16);
  ((unsigned*)(Ab + (size_t)d * 128))[lane] = o;
  if (lane == 0) scoef[d] = dd * (sw + dd);
}

// ---------- final (MFMA bf16, BK=128 single pass) ----------
__global__ __launch_bounds__(256)
void k_final(const u16* __restrict__ Ab, const u16* __restrict__ W2T,
             const float* __restrict__ hc, const float* __restrict__ scoef,
             const float* __restrict__ bg, const float* __restrict__ Wcls,
             const float* __restrict__ bcls, float* __restrict__ out, int N) {
  __shared__ __align__(16) char smem[65536];
  __shared__ float WcS[1280];
  __shared__ float hcS[128], bgS[128], bcS[10];
  u16* As = (u16*)smem;            // [128 rows][128 k] swizzled, 32KB
  u16* Bs = (u16*)(smem + 32768);  // [128 cols][128 k] swizzled, 32KB
  u16* Tb = (u16*)smem;            // reused after compute: [128][136] bf16
  int tid = threadIdx.x;
  for (int i = tid; i < 1280; i += 256) WcS[i] = Wcls[i];
  if (tid < 128) { hcS[tid] = hc[tid]; bgS[tid] = bg[tid]; }
  if (tid < 10) bcS[tid] = bcls[tid];
  int lane = tid & 63, wid = tid >> 6;
  int wm = wid & 1, wn = wid >> 1;
  int bRow = blockIdx.x * 128;

  // stage A and B tiles (whole K=128)
#pragma unroll
  for (int i = 0; i < 8; ++i) {
    int p = i * 256 + tid;
    int row = p >> 4, slot = p & 15, srs = slot ^ (row & 7);
    int gr = bRow + row; if (gr >= N) gr = N - 1;
    gload_lds16(Ab + (size_t)gr * 128 + srs * 8, (char*)As + p * 16);
    gload_lds16(W2T + (size_t)row * 128 + srs * 8, (char*)Bs + p * 16);
  }
  f32x4 acc[4][4];
#pragma unroll
  for (int mi = 0; mi < 4; ++mi)
#pragma unroll
    for (int ni = 0; ni < 4; ++ni) acc[mi][ni] = {0.f, 0.f, 0.f, 0.f};
  __syncthreads();
#pragma unroll
  for (int ks = 0; ks < 4; ++ks) {
    short8 af[4], bfv[4];
#pragma unroll
    for (int mi = 0; mi < 4; ++mi) {
      int row = wm * 64 + mi * 16 + (lane & 15);
      int swz = (ks * 4 + (lane >> 4)) ^ (lane & 7);
      af[mi] = *(const short8*)(As + row * 128 + swz * 8);
    }
#pragma unroll
    for (int ni = 0; ni < 4; ++ni) {
      int row = wn * 64 + ni * 16 + (lane & 15);
      int swz = (ks * 4 + (lane >> 4)) ^ (lane & 7);
      bfv[ni] = *(const short8*)(Bs + row * 128 + swz * 8);
    }
#pragma unroll
    for (int mi = 0; mi < 4; ++mi)
#pragma unroll
      for (int ni = 0; ni < 4; ++ni)
        acc[mi][ni] = __builtin_amdgcn_mfma_f32_16x16x32_bf16(af[mi], bfv[ni], acc[mi][ni], 0, 0, 0);
  }
  __syncthreads();  // all LDS reads done before Tb overwrite

  // epilogue: u = acc + hc*scoef + bg, relu -> Tb (bf16)
  float hcv[4], bgv[4];
#pragma unroll
  for (int ni = 0; ni < 4; ++ni) {
    int n = wn * 64 + ni * 16 + (lane & 15);
    hcv[ni] = hcS[n];
    bgv[ni] = bgS[n];
  }
#pragma unroll
  for (int mi = 0; mi < 4; ++mi) {
#pragma unroll
    for (int r = 0; r < 4; ++r) {
      int m = wm * 64 + mi * 16 + (lane >> 4) * 4 + r;
      int gr = bRow + m;
      float sc = (gr < N) ? scoef[gr] : 0.f;
#pragma unroll
      for (int ni = 0; ni < 4; ++ni) {
        float u = fmaxf(acc[mi][ni][r] + hcv[ni] * sc + bgv[ni], 0.f);
        Tb[m * 136 + wn * 64 + ni * 16 + (lane & 15)] = f2bf(u);
      }
    }
  }
  __syncthreads();

  // classifier + log_softmax: 2 threads per row
  int r2 = tid >> 1, qd = tid & 1;
  float part[10];
#pragma unroll
  for (int t = 0; t < 10; ++t) part[t] = 0.f;
  for (int jj = 0; jj < 64; ++jj) {
    int j = qd * 64 + jj;
    float a = bf2f(Tb[r2 * 136 + j]);
#pragma unroll
    for (int t = 0; t < 10; ++t) part[t] = fmaf(a, WcS[j * 10 + t], part[t]);
  }
#pragma unroll
  for (int t = 0; t < 10; ++t) part[t] += __shfl_xor(part[t], 1);
  int gr = bRow + r2;
  if (qd == 0 && gr < N) {
    float l[10], m = -1e30f;
#pragma unroll
    for (int t = 0; t < 10; ++t) {
      l[t] = part[t] + bcS[t];
      m = fmaxf(m, l[t]);
    }
    float se = 0.f;
#pragma unroll
    for (int t = 0; t < 10; ++t) se += expf(l[t] - m);
    float lse = m + logf(se);
#pragma unroll
    for (int t = 0; t < 10; ++t) out[(size_t)gr * 10 + t] = l[t] - lse;
  }
}

// ---------------------------------------------------------------------------
extern "C" void kernel_launch(void* const* d_in, const int* in_sizes, int n_in,
                              void* d_out, int out_size, void* d_ws, size_t ws_size,
                              hipStream_t stream) {
  const float* X = (const float*)d_in[0];
  const int* ei = (const int*)d_in[2];
  const float* gamma1 = (const float*)d_in[3];
  const float* beta1 = (const float*)d_in[4];
  const float* Wmlp = (const float*)d_in[5];
  const float* bmlp = (const float*)d_in[6];
  const float* gamma2 = (const float*)d_in[7];
  const float* beta2 = (const float*)d_in[8];
  const float* Wgcn = (const float*)d_in[9];
  const float* bgcn = (const float*)d_in[10];
  const float* Wcls = (const float*)d_in[11];
  const float* bcls = (const float*)d_in[12];
  float* out = (float*)d_out;

  const int N = in_sizes[0] / 512;
  const int E = in_sizes[2] / 2;
  const float invN = 1.0f / (float)N;

  char* ws = (char*)d_ws;
  float* s1 = (float*)(ws + 0);            // 512
  float* q1 = (float*)(ws + 2048);         // 512
  float* s2 = (float*)(ws + 4096);         // 128
  float* q2 = (float*)(ws + 4608);         // 128
  float* b1p = (float*)(ws + 5120);        // 128
  float* hconst = (float*)(ws + 5632);     // 128
  u16* W1bT = (u16*)(ws + 8192);           // 128*512 bf16 -> ends 139264
  u16* W2bT = (u16*)(ws + 139264);         // 128*128 bf16 -> ends 172032
  int* bsums = (int*)(ws + 172032);        // 256 -> 173056
  int* deg = (int*)(ws + 173056);          // N
  int* cursor = (int*)(ws + 373056);       // N
  int* offs = (int*)(ws + 573056);         // N
  float* dinv = (float*)(ws + 773056);     // N
  float* scoef = (float*)(ws + 973056);    // N
  int* col = (int*)(ws + 1173056);         // E -> 4373056
  u16* Yb = (u16*)(ws + 4373504);          // N*128 bf16 -> 17173504
  u16* Ab = (u16*)(ws + 17173504);         // N*128 bf16 -> 29973504
  (void)ws_size; (void)n_in; (void)out_size;

  const int* esrc = ei;
  const int* edst = ei + E;
  int nb = (N + 255) / 256;
  int eb = (E + 255) / 256;
  int gb = (N + 127) / 128;  // 391

  // zero stats + b1p + hconst (contiguous 1536 floats at ws+0)
  k_zero<<<6, 256, 0, stream>>>(s1, 1536);
  k_zero<<<(2 * N + 255) / 256, 256, 0, stream>>>((float*)deg, 2 * N);

  k_bn1_stats<<<1024, 512, 0, stream>>>(X, N, s1, q1);
  k_foldwT<<<256, 256, 0, stream>>>(s1, q1, gamma1, Wmlp, W1bT, invN, 9);
  k_foldb_par<<<16, 256, 0, stream>>>(s1, q1, gamma1, beta1, Wmlp, bmlp, b1p, invN, 32);
  k_gemm1<<<gb, 256, 0, stream>>>(X, W1bT, b1p, Yb, s2, q2, N);

  k_deg<<<eb, 256, 0, stream>>>(edst, E, deg);
  k_scan1<<<nb, 256, 0, stream>>>(deg, N, offs, bsums, dinv);
  k_scan2<<<1, 256, 0, stream>>>(bsums, nb);
  k_scan3<<<nb, 256, 0, stream>>>(offs, bsums, N);
  k_scatter<<<eb, 256, 0, stream>>>(esrc, edst, E, offs, cursor, col);

  k_foldwT<<<64, 256, 0, stream>>>(s2, q2, gamma2, Wgcn, W2bT, invN, 7);
  k_foldb_par<<<8, 256, 0, stream>>>(s2, q2, gamma2, beta2, Wgcn, nullptr, hconst, invN, 16);

  k_gather<<<(N + 3) / 4, 256, 0, stream>>>(Yb, col, offs, deg, dinv, Ab, scoef, N);
  k_final<<<gb, 256, 0, stream>>>(Ab, W2bT, hconst, scoef, bgcn, Wcls, bcls, out, N);
}